// Round 4
// baseline (338.806 us; speedup 1.0000x reference)
//
#include <hip/hip_runtime.h>
#include <hip/hip_bf16.h>

// EdgeDetourHead: B=2, N=512, E=128, H=256
// R10: occupancy WITHOUT spill. R9's lesson: launch_bounds(256,4) forced
// regs<=128 while demand was ~175 -> ~400MB scratch traffic (WRITE_SIZE 272MB)
// = the whole regression. Constraint surface: waves/SIMD * regs <= 512 (unified
// VGPR+AGPR pool), WGs/CU * LDS <= 160KB.
// Fix: 512-thread WGs (8 waves), TJ=64. Wave (wm=wave&3, wn=wave>>2) owns
// 2 m-tiles x 1 n-tile -> acc = 32 AGPR (1/4 of R8). Demand ~120 <= 128
// -> 4 waves/SIMD = 16 waves/CU (2 WGs, 50% occ), LDS 2x35KB. No register
// prefetch arrays. Same algorithm (PA/PB hoisted), same total MFMA & LDS volume.
// prep: 4 nodes per PA/PB block (W1 L2 re-reads 268MB -> 67MB).

#define BN 512
#define EE 128
#define HH 256
#define TJ 64            // pair tile (j) per workgroup

typedef __attribute__((ext_vector_type(8)))  short short8;
typedef __attribute__((ext_vector_type(4)))  short short4v;
typedef __attribute__((ext_vector_type(16))) float f32x16;
typedef __attribute__((ext_vector_type(4)))  float f32x4;

static __device__ __forceinline__ unsigned short f2bf(float f) {
    __bf16 h = (__bf16)f;
    return __builtin_bit_cast(unsigned short, h);
}
static __device__ __forceinline__ f32x16 zero16() {
    f32x16 v;
    #pragma unroll
    for (int i = 0; i < 16; ++i) v[i] = 0.f;
    return v;
}
#define MFMA(a, b, c) __builtin_amdgcn_mfma_f32_32x32x16_bf16((a), (b), (c), 0, 0, 0)

// ---------------- kernel 0: prep ----------------
// blocks 0..255: weight pack. Packed frag idx = ((kb*8 + mtile)*64 + l)*8 + t ;
//   value W[kb*16+(l>>5)*8+t][mtile*32+(l&31)]  == A-frag of W^T.
// blocks 256..511: PA[b,i,f] = h_i@W1a + b1 (fp32, row-major) and
//   PBT[b][f>>2][j][f&3] = (h_j@W1b)[f] (fp32, transposed). 4 nodes per block.
__global__ void prep(const float* __restrict__ node, const float* __restrict__ W1,
                     const float* __restrict__ W2, const float* __restrict__ b1,
                     float* __restrict__ PA, float* __restrict__ PBT,
                     unsigned short* __restrict__ w1c_p, unsigned short* __restrict__ w2_p) {
    int blk = blockIdx.x;
    if (blk < 256) {
        int idx = blk * 256 + threadIdx.x;             // 0..65535
        int t = idx & 7, l = (idx >> 3) & 63, mt = (idx >> 9) & 7, kb = idx >> 12;
        int k = kb * 16 + (l >> 5) * 8 + t, m = mt * 32 + (l & 31);
        w2_p[idx] = f2bf(W2[k * HH + m]);              // W2^T A-frags: kb 0..15
        if (idx < 32768)                               // W1c^T: kb 0..7
            w1c_p[idx] = f2bf(W1[(2 * EE + k) * HH + m]);
    } else {
        int bi0 = (blk - 256) * 4;                     // 4 nodes per block
        int h = threadIdx.x;
        float sa[4], sb[4];
        #pragma unroll
        for (int n = 0; n < 4; ++n) { sa[n] = b1[h]; sb[n] = 0.f; }
        #pragma unroll 8
        for (int e = 0; e < EE; ++e) {
            float wa = W1[e * HH + h];
            float wb = W1[(EE + e) * HH + h];
            #pragma unroll
            for (int n = 0; n < 4; ++n) {
                float nv = node[(size_t)(bi0 + n) * EE + e];   // wave-uniform
                sa[n] += nv * wa;
                sb[n] += nv * wb;
            }
        }
        #pragma unroll
        for (int n = 0; n < 4; ++n) {
            int bi = bi0 + n;
            PA[(size_t)bi * HH + h] = sa[n];
            PBT[(((size_t)(bi >> 9) * 64 + (h >> 2)) * BN + (bi & 511)) * 4 + (h & 3)] = sb[n];
        }
    }
}

// ---------------- kernel 1: fused main, transposed (one 64-pair tile per WG) --------
// 8 waves: wm = wave&3 -> m-tiles {2wm, 2wm+1} (64 feats); wn = wave>>2 -> n-tile (32 pairs).
__global__ __launch_bounds__(512, 4) void edge_main(
    const float* __restrict__ node, const float* __restrict__ euclid,
    const float* __restrict__ W1, const float* __restrict__ W3,
    const float* __restrict__ b3, const float* __restrict__ b2v,
    const float* __restrict__ PA, const float* __restrict__ PBT,
    const unsigned short* __restrict__ w1c_p, const unsigned short* __restrict__ w2_p,
    float* __restrict__ out)
{
    // Phase 1/K1: D [64][136] (17408 B) in the low part; after K1 the buffer
    // becomes h1 [64][264] (33792 B). +pp 1 KB -> ~35 KB, 2 blocks/CU (reg-capped).
    __shared__ __align__(16) unsigned short lds_buf[TJ * 264];
    __shared__ float pp[256];

    const int jt = blockIdx.x, i = blockIdx.y, b = blockIdx.z;
    const int jbase = jt * TJ;
    const int tid = threadIdx.x, wave = tid >> 6, lane = tid & 63;
    const int m0 = lane & 31, q = lane >> 5;
    const int wm = wave & 3, wn = wave >> 2;

    unsigned short* ldsD  = lds_buf;                   // [64][136]
    unsigned short* ldsH1 = lds_buf;                   // [64][264], overlays D after K1

    // single-scalar prefetch: this wave's euclid values (pairs wn*32+m0)
    const float ev = euclid[((size_t)b * BN + i) * BN + jbase + wn * 32 + m0];

    // ---- phase 1: build D=|h_i-h_j| (bf16) row-major [pair][e], stride 136 ----
    {
        int row = tid >> 3, oct = tid & 7;             // 8 threads per j-row
        const f32x4* nj = (const f32x4*)(node + ((size_t)b * BN + jbase + row) * EE);
        const f32x4* hv = (const f32x4*)(node + ((size_t)b * BN + i) * EE);
        #pragma unroll
        for (int g = 0; g < 2; ++g) {
            int c0 = oct * 4 + g * 2;                  // f32x4 index
            f32x4 a0 = nj[c0], a1 = nj[c0 + 1];
            f32x4 h0 = hv[c0], h1v = hv[c0 + 1];
            short8 pd;
            #pragma unroll
            for (int u = 0; u < 4; ++u) {
                pd[u]     = (short)f2bf(fabsf(a0[u] - h0[u]));
                pd[4 + u] = (short)f2bf(fabsf(a1[u] - h1v[u]));
            }
            *(short8*)&ldsD[row * 136 + oct * 16 + g * 8] = pd;
        }
    }
    __syncthreads();

    // ---- layer 1 (transposed): C1^T = W1c^T @ D^T, K=128 ----
    f32x16 acc[2];
    acc[0] = zero16(); acc[1] = zero16();
    {
        const short8* wc = (const short8*)w1c_p;
        #pragma unroll
        for (int kb = 0; kb < 8; ++kb) {
            short8 ac0 = wc[(kb * 8 + wm * 2 + 0) * 64 + lane];
            short8 ac1 = wc[(kb * 8 + wm * 2 + 1) * 64 + lane];
            short8 bD = *(const short8*)&ldsD[(wn * 32 + m0) * 136 + kb * 16 + q * 8];
            acc[0] = MFMA(ac0, bD, acc[0]);
            acc[1] = MFMA(ac1, bD, acc[1]);
        }
    }
    __syncthreads();   // D dead; buffer becomes h1

    // ---- epi1: h1[pair][f] = relu(C1^T + PA[i][f] + PB[j][f] + e_ij*w1d[f]) ----
    {
        const float* paB = PA + ((size_t)b * BN + i) * HH;
        const float* wd  = W1 + (size_t)(3 * EE) * HH;           // w1d row (384)
        const float* pbt = PBT + (size_t)b * 64 * BN * 4;
        #pragma unroll
        for (int mt = 0; mt < 2; ++mt) {
            #pragma unroll
            for (int rg = 0; rg < 4; ++rg) {
                int f0 = (wm * 2 + mt) * 32 + rg * 8;            // wave-uniform
                f32x4 plo = *(const f32x4*)&paB[f0];
                f32x4 phi = *(const f32x4*)&paB[f0 + 4];
                f32x4 dlo = *(const f32x4*)&wd[f0];
                f32x4 dhi = *(const f32x4*)&wd[f0 + 4];
                f32x4 pbv = *(const f32x4*)&pbt[
                    (((size_t)(f0 >> 2) + q) * BN + jbase + wn * 32 + m0) * 4];
                short4v w;
                #pragma unroll
                for (int u = 0; u < 4; ++u) {
                    float pav = q ? phi[u] : plo[u];
                    float wdv = q ? dhi[u] : dlo[u];
                    float v = acc[mt][rg * 4 + u] + pav + pbv[u] + ev * wdv;
                    v = v > 0.f ? v : 0.f;
                    w[u] = (short)f2bf(v);
                }
                *(short4v*)&ldsH1[(wn * 32 + m0) * 264 + f0 + 4 * q] = w;
            }
        }
    }
    __syncthreads();

    // ---- layer 2 (transposed): C2^T = W2^T @ h1^T, K=256 ----
    f32x16 c2[2];
    c2[0] = zero16(); c2[1] = zero16();
    {
        const short8* w2f = (const short8*)w2_p;
        #pragma unroll
        for (int kb = 0; kb < 16; ++kb) {
            short8 a0 = w2f[(kb * 8 + wm * 2 + 0) * 64 + lane];
            short8 a1 = w2f[(kb * 8 + wm * 2 + 1) * 64 + lane];
            short8 bh = *(const short8*)&ldsH1[(wn * 32 + m0) * 264 + kb * 16 + q * 8];
            c2[0] = MFMA(a0, bh, c2[0]);
            c2[1] = MFMA(a1, bh, c2[1]);
        }
    }

    // ---- layer 3 in registers: s = sum_feat relu(c2+b2[feat]) * W3[feat] ----
    {
        float s = 0.f;
        #pragma unroll
        for (int mt = 0; mt < 2; ++mt) {
            #pragma unroll
            for (int rg = 0; rg < 4; ++rg) {
                int f0 = (wm * 2 + mt) * 32 + rg * 8;            // wave-uniform
                f32x4 blo = *(const f32x4*)&b2v[f0];
                f32x4 bhi = *(const f32x4*)&b2v[f0 + 4];
                f32x4 wlo = *(const f32x4*)&W3[f0];
                f32x4 whi = *(const f32x4*)&W3[f0 + 4];
                #pragma unroll
                for (int u = 0; u < 4; ++u) {
                    float bb = q ? bhi[u] : blo[u];
                    float ww = q ? whi[u] : wlo[u];
                    float h2 = c2[mt][rg * 4 + u] + bb;
                    h2 = h2 > 0.f ? h2 : 0.f;
                    s += h2 * ww;
                }
            }
        }
        s += __shfl_xor(s, 32, 64);                   // fold q-halves
        if (lane < 32) pp[wave * 32 + lane] = s;
    }
    __syncthreads();
    if (tid < TJ) {
        int wn2 = tid >> 5, l5 = tid & 31;
        float v = pp[(wn2 * 4 + 0) * 32 + l5] + pp[(wn2 * 4 + 1) * 32 + l5]
                + pp[(wn2 * 4 + 2) * 32 + l5] + pp[(wn2 * 4 + 3) * 32 + l5] + b3[0];
        out[((size_t)b * BN + i) * BN + jbase + tid] = v;
    }
}

// ---------------- kernel 2: in-place symmetrize + zero diagonal ----------------
__global__ void symmetrize(float* __restrict__ out) {
    int b = blockIdx.z, ti = blockIdx.y, tj = blockIdx.x;
    if (tj < ti) return;
    int i = ti * 32 + threadIdx.y, j = tj * 32 + threadIdx.x;
    float* p = out + (size_t)b * BN * BN;
    if (i == j) { p[(size_t)i * BN + j] = 0.f; return; }
    if (j < i) return;
    float a = p[(size_t)i * BN + j];
    float c = p[(size_t)j * BN + i];
    float v = 0.5f * (a + c);
    p[(size_t)i * BN + j] = v;
    p[(size_t)j * BN + i] = v;
}

extern "C" void kernel_launch(void* const* d_in, const int* in_sizes, int n_in,
                              void* d_out, int out_size, void* d_ws, size_t ws_size,
                              hipStream_t stream) {
    const float* node   = (const float*)d_in[0];
    const float* euclid = (const float*)d_in[2];
    const float* W1     = (const float*)d_in[3];
    const float* b1     = (const float*)d_in[4];
    const float* W2     = (const float*)d_in[5];
    const float* b2     = (const float*)d_in[6];
    const float* W3     = (const float*)d_in[7];
    const float* b3     = (const float*)d_in[8];
    float* out = (float*)d_out;

    char* ws = (char*)d_ws;
    float*          PA    = (float*)ws;                                   // 1 MB
    float*          PBT   = (float*)(ws + (1u << 20));                    // 1 MB
    unsigned short* w1c_p = (unsigned short*)(ws + (2u << 20));           // 64 KB
    unsigned short* w2_p  = (unsigned short*)(ws + (2u << 20) + 65536);   // 128 KB

    prep<<<512, 256, 0, stream>>>(node, W1, W2, b1, PA, PBT, w1c_p, w2_p);
    edge_main<<<dim3(BN / TJ, BN, 2), 512, 0, stream>>>(
        node, euclid, W1, W3, b3, b2, PA, PBT, w1c_p, w2_p, out);
    symmetrize<<<dim3(BN / 32, BN / 32, 2), dim3(32, 32), 0, stream>>>(out);
}

// Round 5
// 272.493 us; speedup vs baseline: 1.2434x; 1.2434x over previous
//
#include <hip/hip_runtime.h>
#include <hip/hip_bf16.h>

// EdgeDetourHead: B=2, N=512, E=128, H=256
// R11: the untested corner of the {tile, waves} grid.
//   R8  {TJ=128, 4 waves}: 185us — 2 waves/SIMD, 1x frag traffic, 1x WG count
//   R10 {TJ=64,  8 waves}: 286us — 4 waves/SIMD, 4x frag traffic, 2x WG count
//   R11 {TJ=128, 8 waves}:        — 4 waves/SIMD, 2x frag traffic, 1x WG count
// MfmaUtil*dur is constant at ~43us across R8/R9/R10 (the compute floor at
// 32cyc/SIMD per 32x32x16); the rest is within-phase latency that 1 wave/SIMD
// per WG can't hide. 8-wave WGs at TJ=128 double same-phase waves per SIMD
// without R10's 4x overhead blowup. Regs: acc[2][2]=64 AGPR (c2 reuses after
// acc dies) + ~60 VGPR = ~124 <= 128 cap of launch_bounds(512,4) -> no spill.

#define BN 512
#define EE 128
#define HH 256
#define TJ 128           // pair tile (j) per workgroup

typedef __attribute__((ext_vector_type(8)))  short short8;
typedef __attribute__((ext_vector_type(4)))  short short4v;
typedef __attribute__((ext_vector_type(16))) float f32x16;
typedef __attribute__((ext_vector_type(4)))  float f32x4;

static __device__ __forceinline__ unsigned short f2bf(float f) {
    __bf16 h = (__bf16)f;
    return __builtin_bit_cast(unsigned short, h);
}
static __device__ __forceinline__ f32x16 zero16() {
    f32x16 v;
    #pragma unroll
    for (int i = 0; i < 16; ++i) v[i] = 0.f;
    return v;
}
#define MFMA(a, b, c) __builtin_amdgcn_mfma_f32_32x32x16_bf16((a), (b), (c), 0, 0, 0)

// ---------------- kernel 0: prep ----------------
// blocks 0..255: weight pack. Packed frag idx = ((kb*8 + mtile)*64 + l)*8 + t ;
//   value W[kb*16+(l>>5)*8+t][mtile*32+(l&31)]  == A-frag of W^T.
// blocks 256..511: PA[b,i,f] = h_i@W1a + b1 (fp32, row-major) and
//   PBT[b][f>>2][j][f&3] = (h_j@W1b)[f] (fp32, transposed). 4 nodes per block.
__global__ void prep(const float* __restrict__ node, const float* __restrict__ W1,
                     const float* __restrict__ W2, const float* __restrict__ b1,
                     float* __restrict__ PA, float* __restrict__ PBT,
                     unsigned short* __restrict__ w1c_p, unsigned short* __restrict__ w2_p) {
    int blk = blockIdx.x;
    if (blk < 256) {
        int idx = blk * 256 + threadIdx.x;             // 0..65535
        int t = idx & 7, l = (idx >> 3) & 63, mt = (idx >> 9) & 7, kb = idx >> 12;
        int k = kb * 16 + (l >> 5) * 8 + t, m = mt * 32 + (l & 31);
        w2_p[idx] = f2bf(W2[k * HH + m]);              // W2^T A-frags: kb 0..15
        if (idx < 32768)                               // W1c^T: kb 0..7
            w1c_p[idx] = f2bf(W1[(2 * EE + k) * HH + m]);
    } else {
        int bi0 = (blk - 256) * 4;                     // 4 nodes per block
        int h = threadIdx.x;
        float sa[4], sb[4];
        #pragma unroll
        for (int n = 0; n < 4; ++n) { sa[n] = b1[h]; sb[n] = 0.f; }
        #pragma unroll 8
        for (int e = 0; e < EE; ++e) {
            float wa = W1[e * HH + h];
            float wb = W1[(EE + e) * HH + h];
            #pragma unroll
            for (int n = 0; n < 4; ++n) {
                float nv = node[(size_t)(bi0 + n) * EE + e];   // wave-uniform
                sa[n] += nv * wa;
                sb[n] += nv * wb;
            }
        }
        #pragma unroll
        for (int n = 0; n < 4; ++n) {
            int bi = bi0 + n;
            PA[(size_t)bi * HH + h] = sa[n];
            PBT[(((size_t)(bi >> 9) * 64 + (h >> 2)) * BN + (bi & 511)) * 4 + (h & 3)] = sb[n];
        }
    }
}

// ---------------- kernel 1: fused main (one 128-pair tile per 8-wave WG) ----------
// wm = wave&3 -> m-tiles {2wm, 2wm+1} (64 feats); wn = wave>>2 -> pair n-tiles
// {2wn, 2wn+1} (64 pairs). acc[mt][nt] = 64 AGPR.
__global__ __launch_bounds__(512, 4) void edge_main(
    const float* __restrict__ node, const float* __restrict__ euclid,
    const float* __restrict__ W1, const float* __restrict__ W3,
    const float* __restrict__ b3, const float* __restrict__ b2v,
    const float* __restrict__ PA, const float* __restrict__ PBT,
    const unsigned short* __restrict__ w1c_p, const unsigned short* __restrict__ w2_p,
    float* __restrict__ out)
{
    // Phase 1/K1: D [128][136] (34816 B) low part; after K1 the buffer becomes
    // h1 [128][264] (67584 B). +pp 2 KB -> ~70 KB, 2 WGs/CU.
    __shared__ __align__(16) unsigned short lds_buf[TJ * 264];
    __shared__ float pp[512];

    const int jt = blockIdx.x, i = blockIdx.y, b = blockIdx.z;
    const int jbase = jt * TJ;
    const int tid = threadIdx.x, wave = tid >> 6, lane = tid & 63;
    const int m0 = lane & 31, q = lane >> 5;
    const int wm = wave & 3, wn = wave >> 2;

    unsigned short* ldsD  = lds_buf;                   // [128][136]
    unsigned short* ldsH1 = lds_buf;                   // [128][264], overlays D after K1

    // this wave's euclid values: pairs (wn*2+nt)*32 + m0
    const float* erow = euclid + ((size_t)b * BN + i) * BN + jbase;
    float ev[2];
    #pragma unroll
    for (int nt = 0; nt < 2; ++nt) ev[nt] = erow[(wn * 2 + nt) * 32 + m0];

    // ---- phase 1: build D=|h_i-h_j| (bf16) row-major [pair][e], stride 136 ----
    {
        int row = tid >> 2, q4 = tid & 3;              // 4 threads per j-row
        const f32x4* nj = (const f32x4*)(node + ((size_t)b * BN + jbase + row) * EE);
        const f32x4* hv = (const f32x4*)(node + ((size_t)b * BN + i) * EE);
        #pragma unroll
        for (int g = 0; g < 4; ++g) {
            int c0 = q4 * 8 + g * 2;                   // f32x4 index
            f32x4 a0 = nj[c0], a1 = nj[c0 + 1];
            f32x4 h0 = hv[c0], h1v = hv[c0 + 1];
            short8 pd;
            #pragma unroll
            for (int u = 0; u < 4; ++u) {
                pd[u]     = (short)f2bf(fabsf(a0[u] - h0[u]));
                pd[4 + u] = (short)f2bf(fabsf(a1[u] - h1v[u]));
            }
            *(short8*)&ldsD[row * 136 + q4 * 32 + g * 8] = pd;
        }
    }
    __syncthreads();

    // ---- layer 1 (transposed): C1^T = W1c^T @ D^T, K=128 ----
    f32x16 acc[2][2];
    #pragma unroll
    for (int mt = 0; mt < 2; ++mt)
        #pragma unroll
        for (int nt = 0; nt < 2; ++nt) acc[mt][nt] = zero16();
    {
        const short8* wc = (const short8*)w1c_p;
        #pragma unroll
        for (int kb = 0; kb < 8; ++kb) {
            short8 ac0 = wc[(kb * 8 + wm * 2 + 0) * 64 + lane];
            short8 ac1 = wc[(kb * 8 + wm * 2 + 1) * 64 + lane];
            #pragma unroll
            for (int nt = 0; nt < 2; ++nt) {
                short8 bD = *(const short8*)&ldsD[((wn * 2 + nt) * 32 + m0) * 136 + kb * 16 + q * 8];
                acc[0][nt] = MFMA(ac0, bD, acc[0][nt]);
                acc[1][nt] = MFMA(ac1, bD, acc[1][nt]);
            }
        }
    }
    __syncthreads();   // D dead; buffer becomes h1

    // ---- epi1: h1[pair][f] = relu(C1^T + PA[i][f] + PB[j][f] + e_ij*w1d[f]) ----
    {
        const float* paB = PA + ((size_t)b * BN + i) * HH;
        const float* wd  = W1 + (size_t)(3 * EE) * HH;           // w1d row (384)
        const float* pbt = PBT + (size_t)b * 64 * BN * 4;
        #pragma unroll
        for (int mt = 0; mt < 2; ++mt) {
            #pragma unroll
            for (int rg = 0; rg < 4; ++rg) {
                int f0 = (wm * 2 + mt) * 32 + rg * 8;            // wave-uniform
                f32x4 plo = *(const f32x4*)&paB[f0];
                f32x4 phi = *(const f32x4*)&paB[f0 + 4];
                f32x4 dlo = *(const f32x4*)&wd[f0];
                f32x4 dhi = *(const f32x4*)&wd[f0 + 4];
                #pragma unroll
                for (int nt = 0; nt < 2; ++nt) {
                    f32x4 pbv = *(const f32x4*)&pbt[
                        (((size_t)(f0 >> 2) + q) * BN + jbase + (wn * 2 + nt) * 32 + m0) * 4];
                    short4v w;
                    #pragma unroll
                    for (int u = 0; u < 4; ++u) {
                        float pav = q ? phi[u] : plo[u];
                        float wdv = q ? dhi[u] : dlo[u];
                        float v = acc[mt][nt][rg * 4 + u] + pav + pbv[u] + ev[nt] * wdv;
                        v = v > 0.f ? v : 0.f;
                        w[u] = (short)f2bf(v);
                    }
                    *(short4v*)&ldsH1[((wn * 2 + nt) * 32 + m0) * 264 + f0 + 4 * q] = w;
                }
            }
        }
    }
    __syncthreads();

    // ---- layer 2 (transposed): C2^T = W2^T @ h1^T, K=256 ----
    f32x16 c2[2][2];
    #pragma unroll
    for (int mt = 0; mt < 2; ++mt)
        #pragma unroll
        for (int nt = 0; nt < 2; ++nt) c2[mt][nt] = zero16();
    {
        const short8* w2f = (const short8*)w2_p;
        #pragma unroll
        for (int kb = 0; kb < 16; ++kb) {
            short8 a0 = w2f[(kb * 8 + wm * 2 + 0) * 64 + lane];
            short8 a1 = w2f[(kb * 8 + wm * 2 + 1) * 64 + lane];
            #pragma unroll
            for (int nt = 0; nt < 2; ++nt) {
                short8 bh = *(const short8*)&ldsH1[((wn * 2 + nt) * 32 + m0) * 264 + kb * 16 + q * 8];
                c2[0][nt] = MFMA(a0, bh, c2[0][nt]);
                c2[1][nt] = MFMA(a1, bh, c2[1][nt]);
            }
        }
    }

    // ---- layer 3 in registers: s[nt] = sum_feat relu(c2+b2[feat]) * W3[feat] ----
    {
        float s[2] = {0.f, 0.f};
        #pragma unroll
        for (int mt = 0; mt < 2; ++mt) {
            #pragma unroll
            for (int rg = 0; rg < 4; ++rg) {
                int f0 = (wm * 2 + mt) * 32 + rg * 8;            // wave-uniform
                f32x4 blo = *(const f32x4*)&b2v[f0];
                f32x4 bhi = *(const f32x4*)&b2v[f0 + 4];
                f32x4 wlo = *(const f32x4*)&W3[f0];
                f32x4 whi = *(const f32x4*)&W3[f0 + 4];
                #pragma unroll
                for (int u = 0; u < 4; ++u) {
                    float bb = q ? bhi[u] : blo[u];
                    float ww = q ? whi[u] : wlo[u];
                    #pragma unroll
                    for (int nt = 0; nt < 2; ++nt) {
                        float h2 = c2[mt][nt][rg * 4 + u] + bb;
                        h2 = h2 > 0.f ? h2 : 0.f;
                        s[nt] += h2 * ww;
                    }
                }
            }
        }
        #pragma unroll
        for (int nt = 0; nt < 2; ++nt)
            s[nt] += __shfl_xor(s[nt], 32, 64);       // fold q-halves
        if (lane < 32) {
            #pragma unroll
            for (int nt = 0; nt < 2; ++nt)
                pp[(wave * 2 + nt) * 32 + lane] = s[nt];
        }
    }
    __syncthreads();
    if (tid < TJ) {
        // pair p=tid: owned by wn2=p>>6, nt=(p>>5)&1; sum over the 4 wm waves
        int wn2 = tid >> 6, nt = (tid >> 5) & 1, l5 = tid & 31;
        float v = b3[0];
        #pragma unroll
        for (int wm2 = 0; wm2 < 4; ++wm2)
            v += pp[(((wn2 * 4 + wm2) * 2) + nt) * 32 + l5];
        out[((size_t)b * BN + i) * BN + jbase + tid] = v;
    }
}

// ---------------- kernel 2: in-place symmetrize + zero diagonal ----------------
__global__ void symmetrize(float* __restrict__ out) {
    int b = blockIdx.z, ti = blockIdx.y, tj = blockIdx.x;
    if (tj < ti) return;
    int i = ti * 32 + threadIdx.y, j = tj * 32 + threadIdx.x;
    float* p = out + (size_t)b * BN * BN;
    if (i == j) { p[(size_t)i * BN + j] = 0.f; return; }
    if (j < i) return;
    float a = p[(size_t)i * BN + j];
    float c = p[(size_t)j * BN + i];
    float v = 0.5f * (a + c);
    p[(size_t)i * BN + j] = v;
    p[(size_t)j * BN + i] = v;
}

extern "C" void kernel_launch(void* const* d_in, const int* in_sizes, int n_in,
                              void* d_out, int out_size, void* d_ws, size_t ws_size,
                              hipStream_t stream) {
    const float* node   = (const float*)d_in[0];
    const float* euclid = (const float*)d_in[2];
    const float* W1     = (const float*)d_in[3];
    const float* b1     = (const float*)d_in[4];
    const float* W2     = (const float*)d_in[5];
    const float* b2     = (const float*)d_in[6];
    const float* W3     = (const float*)d_in[7];
    const float* b3     = (const float*)d_in[8];
    float* out = (float*)d_out;

    char* ws = (char*)d_ws;
    float*          PA    = (float*)ws;                                   // 1 MB
    float*          PBT   = (float*)(ws + (1u << 20));                    // 1 MB
    unsigned short* w1c_p = (unsigned short*)(ws + (2u << 20));           // 64 KB
    unsigned short* w2_p  = (unsigned short*)(ws + (2u << 20) + 65536);   // 128 KB

    prep<<<512, 256, 0, stream>>>(node, W1, W2, b1, PA, PBT, w1c_p, w2_p);
    edge_main<<<dim3(BN / TJ, BN, 2), 512, 0, stream>>>(
        node, euclid, W1, W3, b3, b2, PA, PBT, w1c_p, w2_p, out);
    symmetrize<<<dim3(BN / 32, BN / 32, 2), dim3(32, 32), 0, stream>>>(out);
}